// Round 3
// baseline (846.481 us; speedup 1.0000x reference)
//
#include <hip/hip_runtime.h>

#define B_ 2
#define N_ 16384
#define M_ 4096
#define D_ 128

typedef __attribute__((ext_vector_type(8))) short s8;     // 8 bf16 (4 VGPRs)
typedef __attribute__((ext_vector_type(4))) float f4;     // MFMA C/D + float4 loads
typedef __attribute__((ext_vector_type(4))) unsigned short us4;
typedef unsigned short u16;

__device__ __forceinline__ u16 f2b(float f) {   // RNE float->bf16
  unsigned int x = __float_as_uint(f);
  unsigned int r = x + 0x7fffu + ((x >> 16) & 1u);
  return (u16)(r >> 16);
}
__device__ __forceinline__ s8 ld8(const u16* p) {
  return *reinterpret_cast<const s8*>(p);
}
// Load 8 consecutive f32 (32B, 16B-aligned) and convert to 8 bf16 lanes.
__device__ __forceinline__ s8 ldcvt8(const float* p) {
  f4 x = *reinterpret_cast<const f4*>(p);
  f4 y = *reinterpret_cast<const f4*>(p + 4);
  s8 r;
  r[0] = (short)f2b(x[0]); r[1] = (short)f2b(x[1]);
  r[2] = (short)f2b(x[2]); r[3] = (short)f2b(x[3]);
  r[4] = (short)f2b(y[0]); r[5] = (short)f2b(y[1]);
  r[6] = (short)f2b(y[2]); r[7] = (short)f2b(y[3]);
  return r;
}
__device__ __forceinline__ f4 mfma16(s8 a, s8 b, f4 c) {
  return __builtin_amdgcn_mfma_f32_16x16x32_bf16(a, b, c, 0, 0, 0);
}
__device__ __forceinline__ float clamp50(float x) {
  return fminf(fmaxf(x, -50.f), 50.f);
}

// Transpose seven 128x128 f32 weight matrices into ws as bf16 Wt[n][k] (B-frags).
__global__ void wtrans(const float* a0, const float* a1, const float* a2, const float* a3,
                       const float* a4, const float* a5, const float* a6, u16* dst) {
  const float* s;
  switch (blockIdx.x) {
    case 0: s = a0; break; case 1: s = a1; break; case 2: s = a2; break;
    case 3: s = a3; break; case 4: s = a4; break; case 5: s = a5; break;
    default: s = a6; break;
  }
  u16* d = dst + blockIdx.x * 16384;
  for (int i = threadIdx.x; i < 16384; i += 256) {
    int r = i >> 7, c = i & 127;
    d[c * 128 + r] = f2b(s[i]);
  }
}

// Fused 2-layer MLP: out = relu(X@W1+b1)@W2+b2 (X f32, out bf16 in ws).
// 64 rows/block, wave owns 16 rows.
// TRANSOUT=1 writes output transposed per batch: out[b][d][n] (for Vt).
template<int TRANSOUT>
__global__ __launch_bounds__(256) void mlp2(const float* __restrict__ X,
    const u16* __restrict__ W1t, const float* __restrict__ b1,
    const u16* __restrict__ W2t, const float* __restrict__ b2,
    u16* __restrict__ out) {
  __shared__ u16 H[64][136];            // stride 136: 16B-aligned rows, conflict-light
  const int tid = threadIdx.x;
  const int wave = tid >> 6, lane = tid & 63;
  const int c16 = lane & 15, quad = lane >> 4;
  const long row0 = (long)blockIdx.x * 64 + wave * 16;

  s8 a[4];
  {
    const float* xr = X + (row0 + c16) * D_ + quad * 8;
    #pragma unroll
    for (int kk = 0; kk < 4; kk++) a[kk] = ldcvt8(xr + kk * 32);
  }
  #pragma unroll
  for (int ns = 0; ns < 8; ns++) {
    f4 acc = {0.f, 0.f, 0.f, 0.f};
    const int c = ns * 16 + c16;
    const u16* wr = W1t + (long)c * 128 + quad * 8;
    #pragma unroll
    for (int kk = 0; kk < 4; kk++) acc = mfma16(a[kk], ld8(wr + kk * 32), acc);
    const float bias = b1[c];
    #pragma unroll
    for (int r = 0; r < 4; r++) {
      float v = acc[r] + bias;
      H[wave * 16 + quad * 4 + r][c] = f2b(v > 0.f ? v : 0.f);
    }
  }
  __syncthreads();                      // fence LDS RAW
  s8 a2[4];
  #pragma unroll
  for (int kk = 0; kk < 4; kk++)
    a2[kk] = *reinterpret_cast<const s8*>(&H[wave * 16 + c16][kk * 32 + quad * 8]);
  #pragma unroll
  for (int ns = 0; ns < 8; ns++) {
    f4 acc = {0.f, 0.f, 0.f, 0.f};
    const int c = ns * 16 + c16;
    const u16* wr = W2t + (long)c * 128 + quad * 8;
    #pragma unroll
    for (int kk = 0; kk < 4; kk++) acc = mfma16(a2[kk], ld8(wr + kk * 32), acc);
    const float bias = b2[c];
    if (TRANSOUT == 0) {
      #pragma unroll
      for (int r = 0; r < 4; r++)
        out[(row0 + quad * 4 + r) * D_ + c] = f2b(acc[r] + bias);
    } else {
      const long g = row0 + quad * 4;       // 4 consecutive rows, same batch
      const long bb = g >> 14;              // / N_
      const long n = g & (N_ - 1);
      us4 pk;
      #pragma unroll
      for (int r = 0; r < 4; r++) pk[r] = f2b(acc[r] + bias);
      *reinterpret_cast<us4*>(out + bb * (long)128 * N_ + (long)c * N_ + n) = pk;
    }
  }
}

// kpv = relu(p_feat@bW1+bb1)@bW2 + relu(|p_xyz-v_xyz|@dW1+db1)@dW2 + (bb2+db2)
__global__ __launch_bounds__(256) void kpv_kernel(
    const float* __restrict__ pf, const float* __restrict__ pxyz, const float* __restrict__ vxyz,
    const u16* __restrict__ bW1t, const float* __restrict__ bb1,
    const u16* __restrict__ bW2t, const float* __restrict__ bb2,
    const float* __restrict__ dW1, const float* __restrict__ db1,
    const u16* __restrict__ dW2t, const float* __restrict__ db2,
    u16* __restrict__ out) {
  __shared__ u16 H[64][136];
  const int tid = threadIdx.x;
  const int wave = tid >> 6, lane = tid & 63;
  const int c16 = lane & 15, quad = lane >> 4;
  const long row0 = (long)blockIdx.x * 64 + wave * 16;

  s8 a[4];
  {
    const float* xr = pf + (row0 + c16) * D_ + quad * 8;
    #pragma unroll
    for (int kk = 0; kk < 4; kk++) a[kk] = ldcvt8(xr + kk * 32);
  }
  // beta layer 1 -> H
  #pragma unroll
  for (int ns = 0; ns < 8; ns++) {
    f4 acc = {0.f, 0.f, 0.f, 0.f};
    const int c = ns * 16 + c16;
    const u16* wr = bW1t + (long)c * 128 + quad * 8;
    #pragma unroll
    for (int kk = 0; kk < 4; kk++) acc = mfma16(a[kk], ld8(wr + kk * 32), acc);
    const float bias = bb1[c];
    #pragma unroll
    for (int r = 0; r < 4; r++) {
      float v = acc[r] + bias;
      H[wave * 16 + quad * 4 + r][c] = f2b(v > 0.f ? v : 0.f);
    }
  }
  __syncthreads();                      // fence: L1 write -> L2 read
  f4 acc2[8];
  #pragma unroll
  for (int ns = 0; ns < 8; ns++) acc2[ns] = (f4){0.f, 0.f, 0.f, 0.f};
  {
    s8 a2[4];
    #pragma unroll
    for (int kk = 0; kk < 4; kk++)
      a2[kk] = *reinterpret_cast<const s8*>(&H[wave * 16 + c16][kk * 32 + quad * 8]);
    #pragma unroll
    for (int ns = 0; ns < 8; ns++) {
      const u16* wr = bW2t + (long)(ns * 16 + c16) * 128 + quad * 8;
      #pragma unroll
      for (int kk = 0; kk < 4; kk++) acc2[ns] = mfma16(a2[kk], ld8(wr + kk * 32), acc2[ns]);
    }
  }
  __syncthreads();                      // fence: beta read -> delta overwrite (WAR)
  // delta hidden (Din=3, VALU) -> overwrite own H rows
  {
    const long bat = ((long)blockIdx.x * 64) / N_;
    const float vx0 = vxyz[bat * 3 + 0];
    const float vx1 = vxyz[bat * 3 + 1];
    const float vx2 = vxyz[bat * 3 + 2];
    for (int i = 0; i < 32; i++) {
      const int e = lane + 64 * i;
      const int rr = e >> 7, cc = e & 127;
      const long gr = row0 + rr;
      const float d0 = fabsf(pxyz[gr * 3 + 0] - vx0);
      const float d1 = fabsf(pxyz[gr * 3 + 1] - vx1);
      const float d2 = fabsf(pxyz[gr * 3 + 2] - vx2);
      float h = d0 * dW1[cc] + d1 * dW1[128 + cc] + d2 * dW1[256 + cc] + db1[cc];
      H[wave * 16 + rr][cc] = f2b(h > 0.f ? h : 0.f);
    }
  }
  __syncthreads();                      // fence: delta write -> delta read
  {
    s8 a2[4];
    #pragma unroll
    for (int kk = 0; kk < 4; kk++)
      a2[kk] = *reinterpret_cast<const s8*>(&H[wave * 16 + c16][kk * 32 + quad * 8]);
    #pragma unroll
    for (int ns = 0; ns < 8; ns++) {
      const u16* wr = dW2t + (long)(ns * 16 + c16) * 128 + quad * 8;
      #pragma unroll
      for (int kk = 0; kk < 4; kk++) acc2[ns] = mfma16(a2[kk], ld8(wr + kk * 32), acc2[ns]);
    }
  }
  #pragma unroll
  for (int ns = 0; ns < 8; ns++) {
    const int c = ns * 16 + c16;
    const float bias = bb2[c] + db2[c];
    #pragma unroll
    for (int r = 0; r < 4; r++)
      out[(row0 + quad * 4 + r) * D_ + c] = f2b(acc2[ns][r] + bias);
  }
}

// Pass 1: inv_colsum[b,n] = 1 / sum_m exp(q[m]·kpv[n]*scale). Wave owns 16 n-cols.
__global__ __launch_bounds__(256) void colsum_k(const u16* __restrict__ q,
    const u16* __restrict__ kpv, float* __restrict__ inv) {
  const int tid = threadIdx.x;
  const int wave = tid >> 6, lane = tid & 63;
  const int c16 = lane & 15, quad = lane >> 4;
  const int b = blockIdx.x >> 8;                 // 256 blocks per batch
  const int nb = (blockIdx.x & 255) * 64 + wave * 16;
  s8 bk[4];
  {
    const u16* kr = kpv + ((long)b * N_ + nb + c16) * D_ + quad * 8;
    #pragma unroll
    for (int kk = 0; kk < 4; kk++) bk[kk] = ld8(kr + kk * 32);
  }
  const float scale = 0.088388347648318447f;     // 1/sqrt(128)
  float sum = 0.f;
  const u16* qb = q + (long)b * M_ * D_;
  for (int m0 = 0; m0 < M_; m0 += 32) {
    #pragma unroll
    for (int ms = 0; ms < 2; ms++) {
      const u16* qr = qb + (long)(m0 + ms * 16 + c16) * D_ + quad * 8;
      f4 acc = {0.f, 0.f, 0.f, 0.f};
      #pragma unroll
      for (int kk = 0; kk < 4; kk++) acc = mfma16(ld8(qr + kk * 32), bk[kk], acc);
      #pragma unroll
      for (int r = 0; r < 4; r++) sum += __expf(clamp50(acc[r] * scale));
    }
  }
  sum += __shfl_xor(sum, 16, 64);
  sum += __shfl_xor(sum, 32, 64);
  if (lane < 16) inv[(long)b * N_ + nb + lane] = 1.f / sum;
}

// Pass 2: out[b,m,d] = sum_n exp(s)*inv_colsum[n] * v[n,d] + v_feat[b,m,d]  (f32 out)
__global__ __launch_bounds__(256) void attn_out(const u16* __restrict__ q,
    const u16* __restrict__ kpv, const u16* __restrict__ vt,
    const float* __restrict__ inv, const float* __restrict__ vfeat,
    float* __restrict__ out) {
  __shared__ u16 P[32][72];                      // stride 72: 16B-aligned, padded
  const int tid = threadIdx.x;
  const int wave = tid >> 6, lane = tid & 63;
  const int c16 = lane & 15, quad = lane >> 4;
  const int b = blockIdx.x >> 7;                 // 128 blocks per batch
  const int m_base = (blockIdx.x & 127) * 32;
  const int msub = wave & 1;
  const int nsw = (wave >> 1) * 32;
  const int dbase = wave * 32;
  const float scale = 0.088388347648318447f;

  s8 aq[4];
  {
    const u16* qr = q + ((long)b * M_ + m_base + msub * 16 + c16) * D_ + quad * 8;
    #pragma unroll
    for (int kk = 0; kk < 4; kk++) aq[kk] = ld8(qr + kk * 32);
  }
  f4 acc[2][2];
  #pragma unroll
  for (int i = 0; i < 2; i++)
    #pragma unroll
    for (int j = 0; j < 2; j++) acc[i][j] = (f4){0.f, 0.f, 0.f, 0.f};

  const u16* kpb = kpv + (long)b * N_ * D_;
  const u16* vtb = vt + (long)b * (long)128 * N_;
  const float* invb = inv + (long)b * N_;

  for (int n0 = 0; n0 < N_; n0 += 64) {
    #pragma unroll
    for (int t = 0; t < 2; t++) {
      const int nc = n0 + nsw + t * 16 + c16;
      const u16* kr = kpb + (long)nc * D_ + quad * 8;
      f4 as = {0.f, 0.f, 0.f, 0.f};
      #pragma unroll
      for (int kk = 0; kk < 4; kk++) as = mfma16(aq[kk], ld8(kr + kk * 32), as);
      const float ic = invb[nc];
      #pragma unroll
      for (int r = 0; r < 4; r++)
        P[msub * 16 + quad * 4 + r][nsw + t * 16 + c16] =
            f2b(__expf(clamp50(as[r] * scale)) * ic);
    }
    __syncthreads();
    s8 ap[2][2];
    #pragma unroll
    for (int i = 0; i < 2; i++)
      #pragma unroll
      for (int kk = 0; kk < 2; kk++)
        ap[i][kk] = *reinterpret_cast<const s8*>(&P[i * 16 + c16][kk * 32 + quad * 8]);
    #pragma unroll
    for (int j = 0; j < 2; j++) {
      const u16* vr = vtb + (long)(dbase + j * 16 + c16) * N_ + n0 + quad * 8;
      #pragma unroll
      for (int kk = 0; kk < 2; kk++) {
        s8 bv = ld8(vr + kk * 32);
        #pragma unroll
        for (int i = 0; i < 2; i++) acc[i][j] = mfma16(ap[i][kk], bv, acc[i][j]);
      }
    }
    __syncthreads();
  }
  #pragma unroll
  for (int i = 0; i < 2; i++)
    #pragma unroll
    for (int j = 0; j < 2; j++) {
      const int d = dbase + j * 16 + c16;
      #pragma unroll
      for (int r = 0; r < 4; r++) {
        const long g = ((long)b * M_ + m_base + i * 16 + quad * 4 + r) * D_ + d;
        out[g] = acc[i][j][r] + vfeat[g];
      }
    }
}

extern "C" void kernel_launch(void* const* d_in, const int* in_sizes, int n_in,
                              void* d_out, int out_size, void* d_ws, size_t ws_size,
                              hipStream_t stream) {
  const float* p_xyz  = (const float*)d_in[0];
  const float* v_xyz  = (const float*)d_in[1];
  const float* p_feat = (const float*)d_in[2];
  const float* v_feat = (const float*)d_in[3];
  const float* aW1 = (const float*)d_in[4],  *ab1 = (const float*)d_in[5];
  const float* aW2 = (const float*)d_in[6],  *ab2 = (const float*)d_in[7];
  const float* bW1 = (const float*)d_in[8],  *bb1 = (const float*)d_in[9];
  const float* bW2 = (const float*)d_in[10], *bb2 = (const float*)d_in[11];
  const float* oW1 = (const float*)d_in[12], *ob1 = (const float*)d_in[13];
  const float* oW2 = (const float*)d_in[14], *ob2 = (const float*)d_in[15];
  const float* dW1 = (const float*)d_in[16], *db1 = (const float*)d_in[17];
  const float* dW2 = (const float*)d_in[18], *db2 = (const float*)d_in[19];

  char* ws = (char*)d_ws;
  u16* wt    = (u16*)ws;                               // 7 * 16384 bf16 elems
  u16* aW1t  = wt + 0 * 16384;
  u16* aW2t  = wt + 1 * 16384;
  u16* bW1t  = wt + 2 * 16384;
  u16* bW2t  = wt + 3 * 16384;
  u16* oW1t  = wt + 4 * 16384;
  u16* oW2t  = wt + 5 * 16384;
  u16* dW2t  = wt + 6 * 16384;
  u16* qbuf  = (u16*)(ws + 262144);                    // B*M*D bf16 = 2 MB
  u16* kpvb  = (u16*)(ws + 262144 + 2097152);          // B*N*D bf16 = 8 MB
  u16* vtb   = (u16*)(ws + 262144 + 2097152 + 8388608);        // Vt = 8 MB
  float* invb = (float*)(ws + 262144 + 2097152 + 8388608 + 8388608); // B*N f32

  wtrans<<<dim3(7), dim3(256), 0, stream>>>(aW1, aW2, bW1, bW2, oW1, oW2, dW2, wt);
  mlp2<0><<<dim3((B_ * M_) / 64), dim3(256), 0, stream>>>(v_feat, aW1t, ab1, aW2t, ab2, qbuf);
  mlp2<1><<<dim3((B_ * N_) / 64), dim3(256), 0, stream>>>(p_feat, oW1t, ob1, oW2t, ob2, vtb);
  kpv_kernel<<<dim3((B_ * N_) / 64), dim3(256), 0, stream>>>(
      p_feat, p_xyz, v_xyz, bW1t, bb1, bW2t, bb2, dW1, db1, dW2t, db2, kpvb);
  colsum_k<<<dim3(B_ * (N_ / 64)), dim3(256), 0, stream>>>(qbuf, kpvb, invb);
  attn_out<<<dim3(B_ * (M_ / 32)), dim3(256), 0, stream>>>(qbuf, kpvb, vtb, invb, v_feat,
                                                           (float*)d_out);
}